// Round 4
// baseline (485.721 us; speedup 1.0000x reference)
//
#include <hip/hip_runtime.h>
#include <hip/hip_bf16.h>

typedef __attribute__((ext_vector_type(8))) short short8;
typedef __attribute__((ext_vector_type(4))) float f32x4;

#define NB   32
#define HH   112
#define WW   112
#define CIN  128
#define OH_  110
#define OW_  110
#define COUT 256
#define NTAP 9
#define NCHUNK 18                      // 9 taps x 2 K-halves of 64
#define M_TOTAL (NB * OH_ * OW_)       // 387200
#define BM 256
#define GRID_M ((M_TOTAL + BM - 1) / BM)   // 1513

__device__ __forceinline__ unsigned short f2bf(float f) {
  union { float f; unsigned u; } v; v.f = f;
  unsigned r = v.u + 0x7fffu + ((v.u >> 16) & 1u);  // round-to-nearest-even
  return (unsigned short)(r >> 16);
}

// Binarize + pack weights per chunk in exact LDS-consumption order:
// flat short8 idx = ((chunk*2 + kk)*16 + nb)*64 + lane  (32 KB per chunk).
// Element: n = nb*16 + (lane&15), ci = (chunk&1)*64 + kk*32 + (lane>>4)*8 + j,
// tap = chunk>>1. kern is [tap][ci][co].
__global__ void prep_weights(const float* __restrict__ kern, short8* __restrict__ bfrag) {
  int idx = blockIdx.x * 256 + threadIdx.x;   // 18*2*16*64 = 36864
  if (idx >= NCHUNK * 2 * 16 * 64) return;
  int lane  = idx & 63;
  int nb    = (idx >> 6) & 15;
  int kk    = (idx >> 10) & 1;
  int chunk = idx >> 11;
  int tap   = chunk >> 1;
  int n     = nb * 16 + (lane & 15);
  int cib   = (chunk & 1) * 64 + kk * 32 + ((lane >> 4) << 3);
  short8 v;
#pragma unroll
  for (int j = 0; j < 8; ++j) {
    float kv = kern[(tap * CIN + cib + j) * COUT + n];
    float hs = fminf(fmaxf((kv + 1.0f) * 0.5f, 0.0f), 1.0f);
    float wb = 2.0f * rintf(hs) - 1.0f;   // {-1,+1}, round-half-even
    v[j] = (short)f2bf(wb);
  }
  bfrag[idx] = v;
}

__device__ __forceinline__ void gload16(const char* g, char* l) {
  __builtin_amdgcn_global_load_lds(
      (const __attribute__((address_space(1))) unsigned int*)g,
      (__attribute__((address_space(3))) unsigned int*)l, 16, 0, 0);
}

__global__ __launch_bounds__(512, 2) void bconv(
    const float* __restrict__ x, const char* __restrict__ bfragB,
    const float* __restrict__ bias, float* __restrict__ out) {
  extern __shared__ char lds[];
  char* A0 = lds;             // 256 rows x 64 k bf16 = 32 KB, XOR-swizzled
  char* A1 = lds + 32768;
  char* B0 = lds + 65536;     // 32 KB fragment-linear
  char* B1 = lds + 98304;

  const int tid  = threadIdx.x;
  const int lane = tid & 63;
  const int wave = tid >> 6;
  const int wm   = wave >> 2;   // 0..1  (128-row half)
  const int wn   = wave & 3;    // 0..3  (64-col band)
  const long m0  = (long)blockIdx.x * BM;

  // ---- A staging: thread covers row srow, k-half (tid&1)*32 (32 floats) ----
  const int srow = tid >> 1;
  long mrow = m0 + srow; if (mrow > M_TOTAL - 1) mrow = M_TOTAL - 1;
  int nimg = (int)(mrow / (OH_ * OW_));
  int r2   = (int)(mrow - (long)nimg * (OH_ * OW_));
  int oh   = r2 / OW_;
  int ow   = r2 - oh * OW_;
  const long xbase = (((long)nimg * HH + oh) * WW + ow) * CIN + (tid & 1) * 32;
  const int wswz = (srow & 7) << 4;
  const int wrow = srow * 128 + ((tid & 1) << 6);   // byte base of this thread's 64 B

  // ---- fragment read addressing ----
  const int aswz = (lane & 7) << 4;
  const int klo  = (lane >> 4) << 4;
  const int arow = (wm * 128 + (lane & 15)) * 128;  // + mi*2048 + k-bytes
  const int brd  = wn * 4096 + lane * 16;           // + kk*16384 + ni*1024
  const int bstg = tid * 16;

  f32x4 acc[8][4];
#pragma unroll
  for (int i = 0; i < 8; ++i)
#pragma unroll
    for (int j = 0; j < 4; ++j) acc[i][j] = (f32x4){0.f, 0.f, 0.f, 0.f};

  float4 av[8];
  // ---- prologue: stage chunk 0 ----
  {
#pragma unroll
    for (int r = 0; r < 4; ++r)
      gload16(bfragB + r * 8192 + bstg, B0 + r * 8192 + bstg);
    const float* xp = x + xbase;
#pragma unroll
    for (int f = 0; f < 8; ++f) av[f] = *(const float4*)(xp + f * 4);
#pragma unroll
    for (int j = 0; j < 4; ++j) {
      short8 v;
      v[0]=(short)f2bf(av[2*j].x); v[1]=(short)f2bf(av[2*j].y);
      v[2]=(short)f2bf(av[2*j].z); v[3]=(short)f2bf(av[2*j].w);
      v[4]=(short)f2bf(av[2*j+1].x); v[5]=(short)f2bf(av[2*j+1].y);
      v[6]=(short)f2bf(av[2*j+1].z); v[7]=(short)f2bf(av[2*j+1].w);
      *(short8*)(A0 + wrow + ((((tid & 1) << 6) + j * 16) ^ wswz) - ((tid & 1) << 6)) = v;
    }
    asm volatile("s_waitcnt lgkmcnt(0)" ::: "memory");
    asm volatile("s_waitcnt vmcnt(0)" ::: "memory");
    __builtin_amdgcn_s_barrier();
  }

#pragma unroll 1
  for (int c = 0; c < NCHUNK; ++c) {
    const char* Ac = (c & 1) ? A1 : A0;
    const char* Bc = (c & 1) ? B1 : B0;
    char* An = (c & 1) ? A0 : A1;
    char* Bn = (c & 1) ? B0 : B1;
    const int pf = (c + 1 < NCHUNK);

    // ======== phase 0 (kk=0) ========
    if (pf) {
      const int c1 = c + 1;
      const int t  = c1 >> 1;
      const long xo = ((t / 3) * WW + (t % 3)) * CIN + (c1 & 1) * 64;
      const float* xp = x + xbase + xo;
#pragma unroll
      for (int f = 0; f < 8; ++f) av[f] = *(const float4*)(xp + f * 4);
      const char* bsrc = bfragB + (long)c1 * 32768;
#pragma unroll
      for (int r = 0; r < 4; ++r)
        gload16(bsrc + r * 8192 + bstg, Bn + r * 8192 + bstg);
    }
    short8 af[8], bf[4];
    {
      const int kb = klo ^ aswz;
#pragma unroll
      for (int mi = 0; mi < 8; ++mi)
        af[mi] = *(const short8*)(Ac + arow + mi * 2048 + kb);
#pragma unroll
      for (int ni = 0; ni < 4; ++ni)
        bf[ni] = *(const short8*)(Bc + brd + ni * 1024);
    }
    __builtin_amdgcn_s_barrier();
    asm volatile("s_waitcnt lgkmcnt(0)" ::: "memory");
    __builtin_amdgcn_sched_barrier(0);
    __builtin_amdgcn_s_setprio(1);
#pragma unroll
    for (int mi = 0; mi < 8; ++mi)
#pragma unroll
      for (int ni = 0; ni < 4; ++ni)
        acc[mi][ni] = __builtin_amdgcn_mfma_f32_16x16x32_bf16(af[mi], bf[ni], acc[mi][ni], 0, 0, 0);
    __builtin_amdgcn_s_setprio(0);
    __builtin_amdgcn_s_barrier();

    // ======== phase 1 (kk=1) ========
    {
      const int kb = (64 + klo) ^ aswz;
#pragma unroll
      for (int mi = 0; mi < 8; ++mi)
        af[mi] = *(const short8*)(Ac + arow + mi * 2048 + kb);
#pragma unroll
      for (int ni = 0; ni < 4; ++ni)
        bf[ni] = *(const short8*)(Bc + 16384 + brd + ni * 1024);
    }
    if (pf) {
      // compiler auto-waits av (vmcnt(4): the 4 B-gloads stay in flight)
#pragma unroll
      for (int j = 0; j < 4; ++j) {
        short8 v;
        v[0]=(short)f2bf(av[2*j].x); v[1]=(short)f2bf(av[2*j].y);
        v[2]=(short)f2bf(av[2*j].z); v[3]=(short)f2bf(av[2*j].w);
        v[4]=(short)f2bf(av[2*j+1].x); v[5]=(short)f2bf(av[2*j+1].y);
        v[6]=(short)f2bf(av[2*j+1].z); v[7]=(short)f2bf(av[2*j+1].w);
        *(short8*)(An + srow * 128 + ((((tid & 1) << 6) + j * 16) ^ wswz)) = v;
      }
    }
    __builtin_amdgcn_s_barrier();
    asm volatile("s_waitcnt lgkmcnt(0)" ::: "memory");
    __builtin_amdgcn_sched_barrier(0);
    __builtin_amdgcn_s_setprio(1);
#pragma unroll
    for (int mi = 0; mi < 8; ++mi)
#pragma unroll
      for (int ni = 0; ni < 4; ++ni)
        acc[mi][ni] = __builtin_amdgcn_mfma_f32_16x16x32_bf16(af[mi], bf[ni], acc[mi][ni], 0, 0, 0);
    __builtin_amdgcn_s_setprio(0);
    if (pf) asm volatile("s_waitcnt vmcnt(0)" ::: "memory");
    __builtin_amdgcn_s_barrier();
  }

  // ---- Epilogue: C/D col=lane&15, row=(lane>>4)*4+r ----
  const int  colb = wn * 64 + (lane & 15);
  const long rowb = m0 + wm * 128 + ((lane >> 4) << 2);
  if (m0 + BM <= M_TOTAL) {
#pragma unroll
    for (int ni = 0; ni < 4; ++ni) {
      const int col = colb + ni * 16;
      const float bv = bias[col];
#pragma unroll
      for (int mi = 0; mi < 8; ++mi)
#pragma unroll
        for (int r = 0; r < 4; ++r)
          out[(rowb + mi * 16 + r) * COUT + col] = acc[mi][ni][r] + bv;
    }
  } else {
#pragma unroll
    for (int ni = 0; ni < 4; ++ni) {
      const int col = colb + ni * 16;
      const float bv = bias[col];
#pragma unroll
      for (int mi = 0; mi < 8; ++mi)
#pragma unroll
        for (int r = 0; r < 4; ++r) {
          const long row = rowb + mi * 16 + r;
          if (row < M_TOTAL) out[row * COUT + col] = acc[mi][ni][r] + bv;
        }
    }
  }
}

extern "C" void kernel_launch(void* const* d_in, const int* in_sizes, int n_in,
                              void* d_out, int out_size, void* d_ws, size_t ws_size,
                              hipStream_t stream) {
  const float* x    = (const float*)d_in[0];
  const float* kern = (const float*)d_in[1];
  const float* bias = (const float*)d_in[2];
  float* out = (float*)d_out;
  short8* bfrag = (short8*)d_ws;   // 18*32768 B = 589824 B

  (void)hipFuncSetAttribute((const void*)bconv,
                            hipFuncAttributeMaxDynamicSharedMemorySize, 131072);

  prep_weights<<<(NCHUNK * 2 * 16 * 64 + 255) / 256, 256, 0, stream>>>(kern, bfrag);
  bconv<<<dim3(GRID_M), dim3(512), 131072, stream>>>(x, (const char*)bfrag, bias, out);
}

// Round 5
// 474.578 us; speedup vs baseline: 1.0235x; 1.0235x over previous
//
#include <hip/hip_runtime.h>
#include <hip/hip_bf16.h>

typedef __attribute__((ext_vector_type(8))) short short8;
typedef __attribute__((ext_vector_type(4))) float f32x4;

#define NB   32
#define HH   112
#define WW   112
#define CIN  128
#define OH_  110
#define OW_  110
#define COUT 256
#define NTAP 9
#define NCHUNK 18                      // 9 taps x 2 K-halves of 64
#define M_TOTAL (NB * OH_ * OW_)       // 387200
#define BM 256
#define GRID_M ((M_TOTAL + BM - 1) / BM)   // 1513

__device__ __forceinline__ unsigned short f2bf(float f) {
  union { float f; unsigned u; } v; v.f = f;
  unsigned r = v.u + 0x7fffu + ((v.u >> 16) & 1u);  // round-to-nearest-even
  return (unsigned short)(r >> 16);
}

// Binarize + pack weights per chunk in exact LDS-consumption order:
// flat short8 idx = ((chunk*2 + kk)*16 + nb)*64 + lane  (32 KB per chunk).
// Element: n = nb*16 + (lane&15), ci = (chunk&1)*64 + kk*32 + (lane>>4)*8 + j,
// tap = chunk>>1. kern is [tap][ci][co].
__global__ void prep_weights(const float* __restrict__ kern, short8* __restrict__ bfrag) {
  int idx = blockIdx.x * 256 + threadIdx.x;   // 18*2*16*64 = 36864
  if (idx >= NCHUNK * 2 * 16 * 64) return;
  int lane  = idx & 63;
  int nb    = (idx >> 6) & 15;
  int kk    = (idx >> 10) & 1;
  int chunk = idx >> 11;
  int tap   = chunk >> 1;
  int n     = nb * 16 + (lane & 15);
  int cib   = (chunk & 1) * 64 + kk * 32 + ((lane >> 4) << 3);
  short8 v;
#pragma unroll
  for (int j = 0; j < 8; ++j) {
    float kv = kern[(tap * CIN + cib + j) * COUT + n];
    float hs = fminf(fmaxf((kv + 1.0f) * 0.5f, 0.0f), 1.0f);
    float wb = 2.0f * rintf(hs) - 1.0f;   // {-1,+1}, round-half-even
    v[j] = (short)f2bf(wb);
  }
  bfrag[idx] = v;
}

__device__ __forceinline__ void gload16(const char* g, char* l) {
  __builtin_amdgcn_global_load_lds(
      (const __attribute__((address_space(1))) unsigned int*)g,
      (__attribute__((address_space(3))) unsigned int*)l, 16, 0, 0);
}

#define LGKM0()  asm volatile("s_waitcnt lgkmcnt(0)" ::: "memory")
#define BAR()    __builtin_amdgcn_s_barrier()
#define SCHED0() __builtin_amdgcn_sched_barrier(0)

__global__ __launch_bounds__(512, 2) void bconv(
    const float* __restrict__ x, const char* __restrict__ bfragB,
    const float* __restrict__ bias, float* __restrict__ out) {
  extern __shared__ char lds[];
  char* A0 = lds;             // 256 rows x 64 k bf16 = 32 KB, XOR-swizzled
  char* A1 = lds + 32768;
  char* B0 = lds + 65536;     // 3-deep B ring, fragment-linear, 32 KB each
  char* B1 = lds + 98304;
  char* B2 = lds + 131072;

  const int tid  = threadIdx.x;
  const int lane = tid & 63;
  const int wave = tid >> 6;
  const int wm   = wave >> 2;   // 0..1  (128-row half)
  const int wn   = wave & 3;    // 0..3  (64-col band)

  // ---- bijective XCD-chunked swizzle (m204): contiguous m-range per XCD ----
  const int q = GRID_M >> 3, r = GRID_M & 7;
  const int xcd = (int)blockIdx.x & 7, ob = (int)blockIdx.x >> 3;
  const int bid = (xcd < r ? xcd * (q + 1) : r * (q + 1) + (xcd - r) * q) + ob;
  const long m0 = (long)bid * BM;

  // ---- A staging: thread covers row srow, k-half (tid&1)*32 floats ----
  const int srow = tid >> 1;
  long mrow = m0 + srow; if (mrow > M_TOTAL - 1) mrow = M_TOTAL - 1;
  int nimg = (int)(mrow / (OH_ * OW_));
  int r2   = (int)(mrow - (long)nimg * (OH_ * OW_));
  int oh   = r2 / OW_;
  int ow   = r2 - oh * OW_;
  const long xbase = (((long)nimg * HH + oh) * WW + ow) * CIN + (tid & 1) * 32;
  const int wswz = (srow & 7) << 4;
  const int wko  = (tid & 1) << 6;          // byte offset of this thread's k-half

  // ---- fragment read addressing ----
  const int aswz = (lane & 7) << 4;
  const int klo  = (lane >> 4) << 4;
  const int arow = (wm * 128 + (lane & 15)) * 128;  // + mi*2048 + k-bytes
  const int brd  = wn * 4096 + lane * 16;           // + kk*16384 + ni*1024
  const int bstg = tid * 16;

  f32x4 acc[8][4];
#pragma unroll
  for (int i = 0; i < 8; ++i)
#pragma unroll
    for (int j = 0; j < 4; ++j) acc[i][j] = (f32x4){0.f, 0.f, 0.f, 0.f};

  float4 av[8];
  // ================= prologue: chunk0 A + B(0), B(1) =================
  {
    const float* xp = x + xbase;
#pragma unroll
    for (int f = 0; f < 8; ++f) av[f] = *(const float4*)(xp + f * 4);
#pragma unroll
    for (int rr = 0; rr < 4; ++rr)
      gload16(bfragB + rr * 8192 + bstg, B0 + rr * 8192 + bstg);
#pragma unroll
    for (int rr = 0; rr < 4; ++rr)
      gload16(bfragB + 32768 + rr * 8192 + bstg, B1 + rr * 8192 + bstg);
    // cvt + write A0 (compiler inserts vmcnt(8) for av)
#pragma unroll
    for (int j = 0; j < 4; ++j) {
      short8 v;
      v[0]=(short)f2bf(av[2*j].x); v[1]=(short)f2bf(av[2*j].y);
      v[2]=(short)f2bf(av[2*j].z); v[3]=(short)f2bf(av[2*j].w);
      v[4]=(short)f2bf(av[2*j+1].x); v[5]=(short)f2bf(av[2*j+1].y);
      v[6]=(short)f2bf(av[2*j+1].z); v[7]=(short)f2bf(av[2*j+1].w);
      *(short8*)(A0 + srow * 128 + ((wko + j * 16) ^ wswz)) = v;
    }
    LGKM0();
    asm volatile("s_waitcnt vmcnt(4)" ::: "memory");   // B(0) landed; B(1) in flight
    BAR();
  }

  int cm3 = 0;
#pragma unroll 1
  for (int c = 0; c < NCHUNK; ++c) {
    const char* Ac = (c & 1) ? A1 : A0;
    char*       An = (c & 1) ? A0 : A1;
    const char* Bc  = (cm3 == 0) ? B0 : ((cm3 == 1) ? B1 : B2);
    char*       Bn2 = (cm3 == 0) ? B2 : ((cm3 == 1) ? B0 : B1);   // (c+2)%3
    cm3 = (cm3 == 2) ? 0 : cm3 + 1;

    short8 af[4], bf[4];

    // ======== ph0: kk=0, mi 0-3; issue x(c+1) ========
#pragma unroll
    for (int mi = 0; mi < 4; ++mi)
      af[mi] = *(const short8*)(Ac + arow + mi * 2048 + (klo ^ aswz));
#pragma unroll
    for (int ni = 0; ni < 4; ++ni)
      bf[ni] = *(const short8*)(Bc + brd + ni * 1024);
    if (c + 1 < NCHUNK) {
      const int t = (c + 1) >> 1;
      const long xo = ((t / 3) * WW + (t % 3)) * CIN + ((c + 1) & 1) * 64;
      const float* xp = x + xbase + xo;
#pragma unroll
      for (int f = 0; f < 8; ++f) av[f] = *(const float4*)(xp + f * 4);
    }
    BAR(); LGKM0(); SCHED0();
    __builtin_amdgcn_s_setprio(1);
#pragma unroll
    for (int mi = 0; mi < 4; ++mi)
#pragma unroll
      for (int ni = 0; ni < 4; ++ni)
        acc[mi][ni] = __builtin_amdgcn_mfma_f32_16x16x32_bf16(af[mi], bf[ni], acc[mi][ni], 0, 0, 0);
    __builtin_amdgcn_s_setprio(0);
    BAR();

    // ======== ph1: kk=0, mi 4-7; issue B(c+2) gloads ========
#pragma unroll
    for (int mi = 0; mi < 4; ++mi)
      af[mi] = *(const short8*)(Ac + arow + (mi + 4) * 2048 + (klo ^ aswz));
    if (c + 2 < NCHUNK) {
      const char* bsrc = bfragB + (long)(c + 2) * 32768;
#pragma unroll
      for (int rr = 0; rr < 4; ++rr)
        gload16(bsrc + rr * 8192 + bstg, Bn2 + rr * 8192 + bstg);
    }
    BAR(); LGKM0(); SCHED0();
    __builtin_amdgcn_s_setprio(1);
#pragma unroll
    for (int mi = 0; mi < 4; ++mi)
#pragma unroll
      for (int ni = 0; ni < 4; ++ni)
        acc[mi + 4][ni] = __builtin_amdgcn_mfma_f32_16x16x32_bf16(af[mi], bf[ni], acc[mi + 4][ni], 0, 0, 0);
    __builtin_amdgcn_s_setprio(0);
    BAR();

    // ======== ph2: kk=1, mi 0-3 ========
#pragma unroll
    for (int mi = 0; mi < 4; ++mi)
      af[mi] = *(const short8*)(Ac + arow + mi * 2048 + ((64 + klo) ^ aswz));
#pragma unroll
    for (int ni = 0; ni < 4; ++ni)
      bf[ni] = *(const short8*)(Bc + 16384 + brd + ni * 1024);
    BAR(); LGKM0(); SCHED0();
    __builtin_amdgcn_s_setprio(1);
#pragma unroll
    for (int mi = 0; mi < 4; ++mi)
#pragma unroll
      for (int ni = 0; ni < 4; ++ni)
        acc[mi][ni] = __builtin_amdgcn_mfma_f32_16x16x32_bf16(af[mi], bf[ni], acc[mi][ni], 0, 0, 0);
    __builtin_amdgcn_s_setprio(0);
    BAR();

    // ======== ph3: kk=1, mi 4-7; cvt+write A(c+1) ========
#pragma unroll
    for (int mi = 0; mi < 4; ++mi)
      af[mi] = *(const short8*)(Ac + arow + (mi + 4) * 2048 + ((64 + klo) ^ aswz));
    if (c + 1 < NCHUNK) {
      // compiler auto-waits av: vmcnt(4) (only B(c+2) issued later) ->
      // also guarantees B(c+1) has landed before the swap barrier.
#pragma unroll
      for (int j = 0; j < 4; ++j) {
        short8 v;
        v[0]=(short)f2bf(av[2*j].x); v[1]=(short)f2bf(av[2*j].y);
        v[2]=(short)f2bf(av[2*j].z); v[3]=(short)f2bf(av[2*j].w);
        v[4]=(short)f2bf(av[2*j+1].x); v[5]=(short)f2bf(av[2*j+1].y);
        v[6]=(short)f2bf(av[2*j+1].z); v[7]=(short)f2bf(av[2*j+1].w);
        *(short8*)(An + srow * 128 + ((wko + j * 16) ^ wswz)) = v;
      }
    }
    BAR(); LGKM0(); SCHED0();
    __builtin_amdgcn_s_setprio(1);
#pragma unroll
    for (int mi = 0; mi < 4; ++mi)
#pragma unroll
      for (int ni = 0; ni < 4; ++ni)
        acc[mi + 4][ni] = __builtin_amdgcn_mfma_f32_16x16x32_bf16(af[mi], bf[ni], acc[mi + 4][ni], 0, 0, 0);
    __builtin_amdgcn_s_setprio(0);
    BAR();   // swap barrier
  }

  // ---- Epilogue: C/D col=lane&15, row=(lane>>4)*4+r ----
  const int  colb = wn * 64 + (lane & 15);
  const long rowb = m0 + wm * 128 + ((lane >> 4) << 2);
  if (m0 + BM <= M_TOTAL) {
#pragma unroll
    for (int ni = 0; ni < 4; ++ni) {
      const int col = colb + ni * 16;
      const float bv = bias[col];
#pragma unroll
      for (int mi = 0; mi < 8; ++mi)
#pragma unroll
        for (int rr = 0; rr < 4; ++rr)
          out[(rowb + mi * 16 + rr) * COUT + col] = acc[mi][ni][rr] + bv;
    }
  } else {
#pragma unroll
    for (int ni = 0; ni < 4; ++ni) {
      const int col = colb + ni * 16;
      const float bv = bias[col];
#pragma unroll
      for (int mi = 0; mi < 8; ++mi)
#pragma unroll
        for (int rr = 0; rr < 4; ++rr) {
          const long row = rowb + mi * 16 + rr;
          if (row < M_TOTAL) out[row * COUT + col] = acc[mi][ni][rr] + bv;
        }
    }
  }
}

extern "C" void kernel_launch(void* const* d_in, const int* in_sizes, int n_in,
                              void* d_out, int out_size, void* d_ws, size_t ws_size,
                              hipStream_t stream) {
  const float* x    = (const float*)d_in[0];
  const float* kern = (const float*)d_in[1];
  const float* bias = (const float*)d_in[2];
  float* out = (float*)d_out;
  short8* bfrag = (short8*)d_ws;   // 18*32768 B = 589824 B

  (void)hipFuncSetAttribute((const void*)bconv,
                            hipFuncAttributeMaxDynamicSharedMemorySize, 163840);

  prep_weights<<<(NCHUNK * 2 * 16 * 64 + 255) / 256, 256, 0, stream>>>(kern, bfrag);
  bconv<<<dim3(GRID_M), dim3(512), 163840, stream>>>(x, (const char*)bfrag, bias, out);
}

// Round 6
// 351.714 us; speedup vs baseline: 1.3810x; 1.3493x over previous
//
#include <hip/hip_runtime.h>
#include <hip/hip_bf16.h>

typedef __attribute__((ext_vector_type(8))) short short8;
typedef __attribute__((ext_vector_type(4))) float f32x4;

#define NB   32
#define HH   112
#define WW   112
#define CIN  128
#define OH_  110
#define OW_  110
#define COUT 256
#define NTAP 9
#define NCHUNK 18                      // 9 taps x 2 K-halves of 64
#define M_TOTAL (NB * OH_ * OW_)       // 387200
#define BM 256
#define GRID_M ((M_TOTAL + BM - 1) / BM)   // 1513
#define XBF_ELEMS ((long)NB * HH * WW * CIN)   // 51380224

__device__ __forceinline__ unsigned short f2bf(float f) {
  union { float f; unsigned u; } v; v.f = f;
  unsigned r = v.u + 0x7fffu + ((v.u >> 16) & 1u);  // round-to-nearest-even
  return (unsigned short)(r >> 16);
}

// ---- x fp32 -> bf16, one pass (exact grid: 25088 blocks x 256 thr x 8 elems)
__global__ void xcvt(const float* __restrict__ x, unsigned short* __restrict__ xbf) {
  long i = ((long)blockIdx.x * 256 + threadIdx.x) * 8;
  float4 a = *(const float4*)(x + i);
  float4 b = *(const float4*)(x + i + 4);
  short8 v;
  v[0]=(short)f2bf(a.x); v[1]=(short)f2bf(a.y); v[2]=(short)f2bf(a.z); v[3]=(short)f2bf(a.w);
  v[4]=(short)f2bf(b.x); v[5]=(short)f2bf(b.y); v[6]=(short)f2bf(b.z); v[7]=(short)f2bf(b.w);
  *(short8*)(xbf + i) = v;
}

// Binarize + pack weights per chunk in exact LDS-consumption order:
// flat short8 idx = ((chunk*2 + kk)*16 + nb)*64 + lane  (32 KB per chunk).
// n = nb*16 + (lane&15), ci = (chunk&1)*64 + kk*32 + (lane>>4)*8 + j, tap = chunk>>1.
__global__ void prep_weights(const float* __restrict__ kern, short8* __restrict__ bfrag) {
  int idx = blockIdx.x * 256 + threadIdx.x;   // 36864
  if (idx >= NCHUNK * 2 * 16 * 64) return;
  int lane  = idx & 63;
  int nb    = (idx >> 6) & 15;
  int kk    = (idx >> 10) & 1;
  int chunk = idx >> 11;
  int tap   = chunk >> 1;
  int n     = nb * 16 + (lane & 15);
  int cib   = (chunk & 1) * 64 + kk * 32 + ((lane >> 4) << 3);
  short8 v;
#pragma unroll
  for (int j = 0; j < 8; ++j) {
    float kv = kern[(tap * CIN + cib + j) * COUT + n];
    float hs = fminf(fmaxf((kv + 1.0f) * 0.5f, 0.0f), 1.0f);
    float wb = 2.0f * rintf(hs) - 1.0f;   // {-1,+1}, round-half-even
    v[j] = (short)f2bf(wb);
  }
  bfrag[idx] = v;
}

__device__ __forceinline__ void gload16(const char* g, char* l) {
  __builtin_amdgcn_global_load_lds(
      (const __attribute__((address_space(1))) unsigned int*)g,
      (__attribute__((address_space(3))) unsigned int*)l, 16, 0, 0);
}

#define LGKM0()  asm volatile("s_waitcnt lgkmcnt(0)" ::: "memory")
#define BAR()    __builtin_amdgcn_s_barrier()
#define SCHED0() __builtin_amdgcn_sched_barrier(0)

// =================== main kernel: A via pre-swizzled global_load_lds ==========
__global__ __launch_bounds__(512, 2) void bconv(
    const unsigned short* __restrict__ xbf, const char* __restrict__ bfragB,
    const float* __restrict__ bias, float* __restrict__ out) {
  extern __shared__ char lds[];
  char* A0 = lds;             // 256 rows x 128 B (64 ci bf16), XOR-swz content
  char* A1 = lds + 32768;
  char* B0 = lds + 65536;     // 3-deep B ring, fragment-linear
  char* B1 = lds + 98304;
  char* B2 = lds + 131072;

  const int tid  = threadIdx.x;
  const int lane = tid & 63;
  const int wave = tid >> 6;
  const int wm   = wave >> 2;
  const int wn   = wave & 3;

  // bijective XCD-chunked swizzle (m204)
  const int q = GRID_M >> 3, r = GRID_M & 7;
  const int xcd = (int)blockIdx.x & 7, ob = (int)blockIdx.x >> 3;
  const int bid = (xcd < r ? xcd * (q + 1) : r * (q + 1) + (xcd - r) * q) + ob;
  const long m0 = (long)bid * BM;

  // ---- A staging source (pre-swizzled): lane stages rows wave*32+i*8+(lane>>3),
  //      16B-chunk (lane&7)^(lane>>3) of the selected 128 B ci-half.
  const int lrow = lane >> 3;
  const int cswz = ((lane & 7) ^ lrow) << 4;
  const char* xbfc = (const char*)xbf;
  long rbase[4];
#pragma unroll
  for (int i = 0; i < 4; ++i) {
    long mrow = m0 + wave * 32 + i * 8 + lrow;
    if (mrow > M_TOTAL - 1) mrow = M_TOTAL - 1;
    int nimg = (int)(mrow / (OH_ * OW_));
    int r2   = (int)(mrow - (long)nimg * (OH_ * OW_));
    int oh   = r2 / OW_;
    int ow   = r2 - oh * OW_;
    rbase[i] = ((((long)nimg * HH + oh) * WW + ow) * CIN) * 2 + cswz;
  }
  const int adoff = wave * 4096 + lane * 16;   // A dest: + i*1024
  const int bstg  = tid * 16;                  // B dest/src slice

#define STAGE_A(Abuf, cN) do {                                               \
    const int t_ = (cN) >> 1;                                                \
    const long xo_ = (((long)(t_ / 3) * WW + (t_ % 3)) * CIN + ((cN) & 1) * 64) * 2; \
    _Pragma("unroll")                                                        \
    for (int i_ = 0; i_ < 4; ++i_)                                           \
      gload16(xbfc + rbase[i_] + xo_, (Abuf) + adoff + i_ * 1024);           \
  } while (0)

#define STAGE_B(Bbuf, cN) do {                                               \
    const char* bsrc_ = bfragB + (long)(cN) * 32768;                         \
    _Pragma("unroll")                                                        \
    for (int r_ = 0; r_ < 4; ++r_)                                           \
      gload16(bsrc_ + r_ * 8192 + bstg, (Bbuf) + r_ * 8192 + bstg);          \
  } while (0)

  // ---- fragment read addressing ----
  const int aswz = (lane & 7) << 4;
  const int klo  = (lane >> 4) << 4;
  const int arow = (wm * 128 + (lane & 15)) * 128;
  const int brd  = wn * 4096 + lane * 16;

  f32x4 acc[8][4];
#pragma unroll
  for (int i = 0; i < 8; ++i)
#pragma unroll
    for (int j = 0; j < 4; ++j) acc[i][j] = (f32x4){0.f, 0.f, 0.f, 0.f};

  // ---- prologue: A(0), B(0) landed; B(1) in flight ----
  STAGE_A(A0, 0);
  STAGE_B(B0, 0);
  STAGE_B(B1, 1);
  asm volatile("s_waitcnt vmcnt(4)" ::: "memory");
  BAR();

  int cm3 = 0;
#pragma unroll 1
  for (int c = 0; c < NCHUNK; ++c) {
    const char* Ac = (c & 1) ? A1 : A0;
    char*       An = (c & 1) ? A0 : A1;
    const char* Bc  = (cm3 == 0) ? B0 : ((cm3 == 1) ? B1 : B2);
    char*       Bn2 = (cm3 == 0) ? B2 : ((cm3 == 1) ? B0 : B1);
    cm3 = (cm3 == 2) ? 0 : cm3 + 1;

    short8 af[4], bf[4];

    // ---- ph0: kk=0 mi0-3; issue A(c+1) ----
#pragma unroll
    for (int mi = 0; mi < 4; ++mi)
      af[mi] = *(const short8*)(Ac + arow + mi * 2048 + (klo ^ aswz));
#pragma unroll
    for (int ni = 0; ni < 4; ++ni)
      bf[ni] = *(const short8*)(Bc + brd + ni * 1024);
    if (c + 1 < NCHUNK) STAGE_A(An, c + 1);
    BAR(); LGKM0(); SCHED0();
    __builtin_amdgcn_s_setprio(1);
#pragma unroll
    for (int mi = 0; mi < 4; ++mi)
#pragma unroll
      for (int ni = 0; ni < 4; ++ni)
        acc[mi][ni] = __builtin_amdgcn_mfma_f32_16x16x32_bf16(af[mi], bf[ni], acc[mi][ni], 0, 0, 0);
    __builtin_amdgcn_s_setprio(0);
    BAR();

    // ---- ph1: kk=0 mi4-7; issue B(c+2) ----
#pragma unroll
    for (int mi = 0; mi < 4; ++mi)
      af[mi] = *(const short8*)(Ac + arow + (mi + 4) * 2048 + (klo ^ aswz));
    if (c + 2 < NCHUNK) STAGE_B(Bn2, c + 2);
    BAR(); LGKM0(); SCHED0();
    __builtin_amdgcn_s_setprio(1);
#pragma unroll
    for (int mi = 0; mi < 4; ++mi)
#pragma unroll
      for (int ni = 0; ni < 4; ++ni)
        acc[mi + 4][ni] = __builtin_amdgcn_mfma_f32_16x16x32_bf16(af[mi], bf[ni], acc[mi + 4][ni], 0, 0, 0);
    __builtin_amdgcn_s_setprio(0);
    BAR();

    // ---- ph2: kk=1 mi0-3 ----
#pragma unroll
    for (int mi = 0; mi < 4; ++mi)
      af[mi] = *(const short8*)(Ac + arow + mi * 2048 + ((64 + klo) ^ aswz));
#pragma unroll
    for (int ni = 0; ni < 4; ++ni)
      bf[ni] = *(const short8*)(Bc + 16384 + brd + ni * 1024);
    BAR(); LGKM0(); SCHED0();
    __builtin_amdgcn_s_setprio(1);
#pragma unroll
    for (int mi = 0; mi < 4; ++mi)
#pragma unroll
      for (int ni = 0; ni < 4; ++ni)
        acc[mi][ni] = __builtin_amdgcn_mfma_f32_16x16x32_bf16(af[mi], bf[ni], acc[mi][ni], 0, 0, 0);
    __builtin_amdgcn_s_setprio(0);
    BAR();

    // ---- ph3: kk=1 mi4-7; counted end-of-chunk wait ----
#pragma unroll
    for (int mi = 0; mi < 4; ++mi)
      af[mi] = *(const short8*)(Ac + arow + (mi + 4) * 2048 + ((64 + klo) ^ aswz));
    BAR(); LGKM0(); SCHED0();
    __builtin_amdgcn_s_setprio(1);
#pragma unroll
    for (int mi = 0; mi < 4; ++mi)
#pragma unroll
      for (int ni = 0; ni < 4; ++ni)
        acc[mi + 4][ni] = __builtin_amdgcn_mfma_f32_16x16x32_bf16(af[mi], bf[ni], acc[mi + 4][ni], 0, 0, 0);
    __builtin_amdgcn_s_setprio(0);
    if (c < NCHUNK - 2) asm volatile("s_waitcnt vmcnt(4)" ::: "memory");
    else                asm volatile("s_waitcnt vmcnt(0)" ::: "memory");
    BAR();
  }
#undef STAGE_A
#undef STAGE_B

  // ---- Epilogue ----
  const int  colb = wn * 64 + (lane & 15);
  const long rowb = m0 + wm * 128 + ((lane >> 4) << 2);
  if (m0 + BM <= M_TOTAL) {
#pragma unroll
    for (int ni = 0; ni < 4; ++ni) {
      const int col = colb + ni * 16;
      const float bv = bias[col];
#pragma unroll
      for (int mi = 0; mi < 8; ++mi)
#pragma unroll
        for (int rr = 0; rr < 4; ++rr)
          out[(rowb + mi * 16 + rr) * COUT + col] = acc[mi][ni][rr] + bv;
    }
  } else {
#pragma unroll
    for (int ni = 0; ni < 4; ++ni) {
      const int col = colb + ni * 16;
      const float bv = bias[col];
#pragma unroll
      for (int mi = 0; mi < 8; ++mi)
#pragma unroll
        for (int rr = 0; rr < 4; ++rr) {
          const long row = rowb + mi * 16 + rr;
          if (row < M_TOTAL) out[row * COUT + col] = acc[mi][ni][rr] + bv;
        }
    }
  }
}

// =================== fallback (R5 kernel, used only if ws too small) ==========
__global__ __launch_bounds__(512, 2) void bconv_fb(
    const float* __restrict__ x, const char* __restrict__ bfragB,
    const float* __restrict__ bias, float* __restrict__ out) {
  extern __shared__ char lds[];
  char* A0 = lds;
  char* A1 = lds + 32768;
  char* B0 = lds + 65536;
  char* B1 = lds + 98304;
  char* B2 = lds + 131072;

  const int tid  = threadIdx.x;
  const int lane = tid & 63;
  const int wave = tid >> 6;
  const int wm   = wave >> 2;
  const int wn   = wave & 3;
  const int q = GRID_M >> 3, r = GRID_M & 7;
  const int xcd = (int)blockIdx.x & 7, ob = (int)blockIdx.x >> 3;
  const int bid = (xcd < r ? xcd * (q + 1) : r * (q + 1) + (xcd - r) * q) + ob;
  const long m0 = (long)bid * BM;

  const int srow = tid >> 1;
  long mrow = m0 + srow; if (mrow > M_TOTAL - 1) mrow = M_TOTAL - 1;
  int nimg = (int)(mrow / (OH_ * OW_));
  int r2   = (int)(mrow - (long)nimg * (OH_ * OW_));
  int oh   = r2 / OW_;
  int ow   = r2 - oh * OW_;
  const long xbase = (((long)nimg * HH + oh) * WW + ow) * CIN + (tid & 1) * 32;
  const int wswz = (srow & 7) << 4;
  const int wko  = (tid & 1) << 6;
  const int aswz = (lane & 7) << 4;
  const int klo  = (lane >> 4) << 4;
  const int arow = (wm * 128 + (lane & 15)) * 128;
  const int brd  = wn * 4096 + lane * 16;
  const int bstg = tid * 16;

  f32x4 acc[8][4];
#pragma unroll
  for (int i = 0; i < 8; ++i)
#pragma unroll
    for (int j = 0; j < 4; ++j) acc[i][j] = (f32x4){0.f, 0.f, 0.f, 0.f};

  float4 av[8];
  {
    const float* xp = x + xbase;
#pragma unroll
    for (int f = 0; f < 8; ++f) av[f] = *(const float4*)(xp + f * 4);
#pragma unroll
    for (int rr = 0; rr < 4; ++rr)
      gload16(bfragB + rr * 8192 + bstg, B0 + rr * 8192 + bstg);
#pragma unroll
    for (int rr = 0; rr < 4; ++rr)
      gload16(bfragB + 32768 + rr * 8192 + bstg, B1 + rr * 8192 + bstg);
#pragma unroll
    for (int j = 0; j < 4; ++j) {
      short8 v;
      v[0]=(short)f2bf(av[2*j].x); v[1]=(short)f2bf(av[2*j].y);
      v[2]=(short)f2bf(av[2*j].z); v[3]=(short)f2bf(av[2*j].w);
      v[4]=(short)f2bf(av[2*j+1].x); v[5]=(short)f2bf(av[2*j+1].y);
      v[6]=(short)f2bf(av[2*j+1].z); v[7]=(short)f2bf(av[2*j+1].w);
      *(short8*)(A0 + srow * 128 + ((wko + j * 16) ^ wswz)) = v;
    }
    LGKM0();
    asm volatile("s_waitcnt vmcnt(4)" ::: "memory");
    BAR();
  }

  int cm3 = 0;
#pragma unroll 1
  for (int c = 0; c < NCHUNK; ++c) {
    const char* Ac = (c & 1) ? A1 : A0;
    char*       An = (c & 1) ? A0 : A1;
    const char* Bc  = (cm3 == 0) ? B0 : ((cm3 == 1) ? B1 : B2);
    char*       Bn2 = (cm3 == 0) ? B2 : ((cm3 == 1) ? B0 : B1);
    cm3 = (cm3 == 2) ? 0 : cm3 + 1;
    short8 af[4], bf[4];

#pragma unroll
    for (int mi = 0; mi < 4; ++mi)
      af[mi] = *(const short8*)(Ac + arow + mi * 2048 + (klo ^ aswz));
#pragma unroll
    for (int ni = 0; ni < 4; ++ni)
      bf[ni] = *(const short8*)(Bc + brd + ni * 1024);
    if (c + 1 < NCHUNK) {
      const int t = (c + 1) >> 1;
      const long xo = ((t / 3) * WW + (t % 3)) * CIN + ((c + 1) & 1) * 64;
      const float* xp = x + xbase + xo;
#pragma unroll
      for (int f = 0; f < 8; ++f) av[f] = *(const float4*)(xp + f * 4);
    }
    BAR(); LGKM0(); SCHED0();
    __builtin_amdgcn_s_setprio(1);
#pragma unroll
    for (int mi = 0; mi < 4; ++mi)
#pragma unroll
      for (int ni = 0; ni < 4; ++ni)
        acc[mi][ni] = __builtin_amdgcn_mfma_f32_16x16x32_bf16(af[mi], bf[ni], acc[mi][ni], 0, 0, 0);
    __builtin_amdgcn_s_setprio(0);
    BAR();

#pragma unroll
    for (int mi = 0; mi < 4; ++mi)
      af[mi] = *(const short8*)(Ac + arow + (mi + 4) * 2048 + (klo ^ aswz));
    if (c + 2 < NCHUNK) {
      const char* bsrc = bfragB + (long)(c + 2) * 32768;
#pragma unroll
      for (int rr = 0; rr < 4; ++rr)
        gload16(bsrc + rr * 8192 + bstg, Bn2 + rr * 8192 + bstg);
    }
    BAR(); LGKM0(); SCHED0();
    __builtin_amdgcn_s_setprio(1);
#pragma unroll
    for (int mi = 0; mi < 4; ++mi)
#pragma unroll
      for (int ni = 0; ni < 4; ++ni)
        acc[mi + 4][ni] = __builtin_amdgcn_mfma_f32_16x16x32_bf16(af[mi], bf[ni], acc[mi + 4][ni], 0, 0, 0);
    __builtin_amdgcn_s_setprio(0);
    BAR();

#pragma unroll
    for (int mi = 0; mi < 4; ++mi)
      af[mi] = *(const short8*)(Ac + arow + mi * 2048 + ((64 + klo) ^ aswz));
#pragma unroll
    for (int ni = 0; ni < 4; ++ni)
      bf[ni] = *(const short8*)(Bc + 16384 + brd + ni * 1024);
    BAR(); LGKM0(); SCHED0();
    __builtin_amdgcn_s_setprio(1);
#pragma unroll
    for (int mi = 0; mi < 4; ++mi)
#pragma unroll
      for (int ni = 0; ni < 4; ++ni)
        acc[mi][ni] = __builtin_amdgcn_mfma_f32_16x16x32_bf16(af[mi], bf[ni], acc[mi][ni], 0, 0, 0);
    __builtin_amdgcn_s_setprio(0);
    BAR();

#pragma unroll
    for (int mi = 0; mi < 4; ++mi)
      af[mi] = *(const short8*)(Ac + arow + (mi + 4) * 2048 + ((64 + klo) ^ aswz));
    if (c + 1 < NCHUNK) {
#pragma unroll
      for (int j = 0; j < 4; ++j) {
        short8 v;
        v[0]=(short)f2bf(av[2*j].x); v[1]=(short)f2bf(av[2*j].y);
        v[2]=(short)f2bf(av[2*j].z); v[3]=(short)f2bf(av[2*j].w);
        v[4]=(short)f2bf(av[2*j+1].x); v[5]=(short)f2bf(av[2*j+1].y);
        v[6]=(short)f2bf(av[2*j+1].z); v[7]=(short)f2bf(av[2*j+1].w);
        *(short8*)(An + srow * 128 + ((wko + j * 16) ^ wswz)) = v;
      }
    }
    BAR(); LGKM0(); SCHED0();
    __builtin_amdgcn_s_setprio(1);
#pragma unroll
    for (int mi = 0; mi < 4; ++mi)
#pragma unroll
      for (int ni = 0; ni < 4; ++ni)
        acc[mi + 4][ni] = __builtin_amdgcn_mfma_f32_16x16x32_bf16(af[mi], bf[ni], acc[mi + 4][ni], 0, 0, 0);
    __builtin_amdgcn_s_setprio(0);
    BAR();
  }

  const int  colb = wn * 64 + (lane & 15);
  const long rowb = m0 + wm * 128 + ((lane >> 4) << 2);
#pragma unroll
  for (int ni = 0; ni < 4; ++ni) {
    const int col = colb + ni * 16;
    const float bv = bias[col];
#pragma unroll
    for (int mi = 0; mi < 8; ++mi)
#pragma unroll
      for (int rr = 0; rr < 4; ++rr) {
        const long row = rowb + mi * 16 + rr;
        if (row < M_TOTAL) out[row * COUT + col] = acc[mi][ni][rr] + bv;
      }
  }
}

extern "C" void kernel_launch(void* const* d_in, const int* in_sizes, int n_in,
                              void* d_out, int out_size, void* d_ws, size_t ws_size,
                              hipStream_t stream) {
  const float* x    = (const float*)d_in[0];
  const float* kern = (const float*)d_in[1];
  const float* bias = (const float*)d_in[2];
  float* out = (float*)d_out;

  const size_t BPACK_BYTES = (size_t)NCHUNK * 32768;       // 589824
  const size_t XBF_BYTES   = (size_t)XBF_ELEMS * 2;        // 102760448

  if (ws_size >= XBF_BYTES + BPACK_BYTES) {
    unsigned short* xbf = (unsigned short*)d_ws;
    short8* bfrag = (short8*)((char*)d_ws + XBF_BYTES);
    (void)hipFuncSetAttribute((const void*)bconv,
                              hipFuncAttributeMaxDynamicSharedMemorySize, 163840);
    xcvt<<<dim3((unsigned)(XBF_ELEMS / (256 * 8))), dim3(256), 0, stream>>>(x, xbf);
    prep_weights<<<dim3(144), dim3(256), 0, stream>>>(kern, bfrag);
    bconv<<<dim3(GRID_M), dim3(512), 163840, stream>>>(xbf, (const char*)bfrag, bias, out);
  } else {
    short8* bfrag = (short8*)d_ws;
    (void)hipFuncSetAttribute((const void*)bconv_fb,
                              hipFuncAttributeMaxDynamicSharedMemorySize, 163840);
    prep_weights<<<dim3(144), dim3(256), 0, stream>>>(kern, bfrag);
    bconv_fb<<<dim3(GRID_M), dim3(512), 163840, stream>>>(x, (const char*)bfrag, bias, out);
  }
}

// Round 7
// 337.693 us; speedup vs baseline: 1.4384x; 1.0415x over previous
//
#include <hip/hip_runtime.h>
#include <hip/hip_bf16.h>

typedef __attribute__((ext_vector_type(8))) short short8;
typedef __attribute__((ext_vector_type(4))) float f32x4;

#define NB   32
#define HH   112
#define WW   112
#define CIN  128
#define OH_  110
#define OW_  110
#define COUT 256
#define NTAP 9
#define NCHUNK 18                      // 9 taps x 2 K-halves of 64
#define M_TOTAL (NB * OH_ * OW_)       // 387200
#define BM 256
#define GRID_M ((M_TOTAL + BM - 1) / BM)   // 1513
#define XBF_ELEMS ((long)NB * HH * WW * CIN)   // 51380224

__device__ __forceinline__ unsigned short f2bf(float f) {
  union { float f; unsigned u; } v; v.f = f;
  unsigned r = v.u + 0x7fffu + ((v.u >> 16) & 1u);  // round-to-nearest-even
  return (unsigned short)(r >> 16);
}

// ---- x fp32 -> bf16, one pass
__global__ void xcvt(const float* __restrict__ x, unsigned short* __restrict__ xbf) {
  long i = ((long)blockIdx.x * 256 + threadIdx.x) * 8;
  float4 a = *(const float4*)(x + i);
  float4 b = *(const float4*)(x + i + 4);
  short8 v;
  v[0]=(short)f2bf(a.x); v[1]=(short)f2bf(a.y); v[2]=(short)f2bf(a.z); v[3]=(short)f2bf(a.w);
  v[4]=(short)f2bf(b.x); v[5]=(short)f2bf(b.y); v[6]=(short)f2bf(b.z); v[7]=(short)f2bf(b.w);
  *(short8*)(xbf + i) = v;
}

// Binarize + pack weights per chunk in exact LDS-consumption order:
// flat short8 idx = ((chunk*2 + kk)*16 + nb)*64 + lane  (32 KB per chunk).
// n = nb*16 + (lane&15), ci = (chunk&1)*64 + kk*32 + (lane>>4)*8 + j, tap = chunk>>1.
__global__ void prep_weights(const float* __restrict__ kern, short8* __restrict__ bfrag) {
  int idx = blockIdx.x * 256 + threadIdx.x;   // 36864
  if (idx >= NCHUNK * 2 * 16 * 64) return;
  int lane  = idx & 63;
  int nb    = (idx >> 6) & 15;
  int kk    = (idx >> 10) & 1;
  int chunk = idx >> 11;
  int tap   = chunk >> 1;
  int n     = nb * 16 + (lane & 15);
  int cib   = (chunk & 1) * 64 + kk * 32 + ((lane >> 4) << 3);
  short8 v;
#pragma unroll
  for (int j = 0; j < 8; ++j) {
    float kv = kern[(tap * CIN + cib + j) * COUT + n];
    float hs = fminf(fmaxf((kv + 1.0f) * 0.5f, 0.0f), 1.0f);
    float wb = 2.0f * rintf(hs) - 1.0f;   // {-1,+1}, round-half-even
    v[j] = (short)f2bf(wb);
  }
  bfrag[idx] = v;
}

__device__ __forceinline__ void gload16(const char* g, char* l) {
  __builtin_amdgcn_global_load_lds(
      (const __attribute__((address_space(1))) unsigned int*)g,
      (__attribute__((address_space(3))) unsigned int*)l, 16, 0, 0);
}

#define LGKM0()  asm volatile("s_waitcnt lgkmcnt(0)" ::: "memory")
#define BAR()    __builtin_amdgcn_s_barrier()
#define SCHED0() __builtin_amdgcn_sched_barrier(0)

// =================== main kernel: 1 barrier per chunk, counted vmcnt =========
__global__ __launch_bounds__(512, 2) void bconv(
    const unsigned short* __restrict__ xbf, const char* __restrict__ bfragB,
    const float* __restrict__ bias, float* __restrict__ out) {
  extern __shared__ char lds[];
  char* A0 = lds;             // 256 rows x 128 B (64 ci bf16), XOR-swz content
  char* A1 = lds + 32768;
  char* B0 = lds + 65536;     // 3-deep B ring, fragment-linear
  char* B1 = lds + 98304;
  char* B2 = lds + 131072;

  const int tid  = threadIdx.x;
  const int lane = tid & 63;
  const int wave = tid >> 6;
  const int wm   = wave >> 2;
  const int wn   = wave & 3;

  // bijective XCD-chunked swizzle (m204)
  const int q = GRID_M >> 3, r = GRID_M & 7;
  const int xcd = (int)blockIdx.x & 7, ob = (int)blockIdx.x >> 3;
  const int bid = (xcd < r ? xcd * (q + 1) : r * (q + 1) + (xcd - r) * q) + ob;
  const long m0 = (long)bid * BM;

  // ---- A staging source (pre-swizzled): lane stages rows wave*32+i*8+(lane>>3),
  //      16B-chunk (lane&7)^(lane>>3) of the selected 128 B ci-half.
  const int lrow = lane >> 3;
  const int cswz = ((lane & 7) ^ lrow) << 4;
  const char* xbfc = (const char*)xbf;
  long rbase[4];
#pragma unroll
  for (int i = 0; i < 4; ++i) {
    long mrow = m0 + wave * 32 + i * 8 + lrow;
    if (mrow > M_TOTAL - 1) mrow = M_TOTAL - 1;
    int nimg = (int)(mrow / (OH_ * OW_));
    int r2   = (int)(mrow - (long)nimg * (OH_ * OW_));
    int oh   = r2 / OW_;
    int ow   = r2 - oh * OW_;
    rbase[i] = ((((long)nimg * HH + oh) * WW + ow) * CIN) * 2 + cswz;
  }
  const int adoff = wave * 4096 + lane * 16;   // A dest: + i*1024
  const int bstg  = tid * 16;                  // B dest/src slice

#define STAGE_A(Abuf, cN) do {                                               \
    const int t_ = (cN) >> 1;                                                \
    const long xo_ = (((long)(t_ / 3) * WW + (t_ % 3)) * CIN + ((cN) & 1) * 64) * 2; \
    _Pragma("unroll")                                                        \
    for (int i_ = 0; i_ < 4; ++i_)                                           \
      gload16(xbfc + rbase[i_] + xo_, (Abuf) + adoff + i_ * 1024);           \
  } while (0)

#define STAGE_B(Bbuf, cN) do {                                               \
    const char* bsrc_ = bfragB + (long)(cN) * 32768;                         \
    _Pragma("unroll")                                                        \
    for (int r_ = 0; r_ < 4; ++r_)                                           \
      gload16(bsrc_ + r_ * 8192 + bstg, (Bbuf) + r_ * 8192 + bstg);          \
  } while (0)

  // ---- fragment read addressing ----
  const int aswz = (lane & 7) << 4;
  const int klo  = (lane >> 4) << 4;
  const int arow = (wm * 128 + (lane & 15)) * 128;
  const int brd  = wn * 4096 + lane * 16;

  f32x4 acc[8][4];
#pragma unroll
  for (int i = 0; i < 8; ++i)
#pragma unroll
    for (int j = 0; j < 4; ++j) acc[i][j] = (f32x4){0.f, 0.f, 0.f, 0.f};

  // ---- prologue: A(0), B(0) landed; B(1) in flight ----
  STAGE_A(A0, 0);
  STAGE_B(B0, 0);
  STAGE_B(B1, 1);
  asm volatile("s_waitcnt vmcnt(4)" ::: "memory");
  BAR();

  int cm3 = 0;
#pragma unroll 1
  for (int c = 0; c < NCHUNK; ++c) {
    const char* Ac = (c & 1) ? A1 : A0;
    char*       An = (c & 1) ? A0 : A1;
    const char* Bc  = (cm3 == 0) ? B0 : ((cm3 == 1) ? B1 : B2);
    char*       Bn2 = (cm3 == 0) ? B2 : ((cm3 == 1) ? B0 : B1);
    cm3 = (cm3 == 2) ? 0 : cm3 + 1;

    short8 af[4], bf[4];

    // ---- kk=0, mi 0-3 ----
#pragma unroll
    for (int mi = 0; mi < 4; ++mi)
      af[mi] = *(const short8*)(Ac + arow + mi * 2048 + (klo ^ aswz));
#pragma unroll
    for (int ni = 0; ni < 4; ++ni)
      bf[ni] = *(const short8*)(Bc + brd + ni * 1024);
    // prefetch next A / next-next B (to inactive buffers; no reader this chunk)
    if (c + 1 < NCHUNK) STAGE_A(An, c + 1);
    if (c + 2 < NCHUNK) STAGE_B(Bn2, c + 2);
#pragma unroll
    for (int mi = 0; mi < 4; ++mi)
#pragma unroll
      for (int ni = 0; ni < 4; ++ni)
        acc[mi][ni] = __builtin_amdgcn_mfma_f32_16x16x32_bf16(af[mi], bf[ni], acc[mi][ni], 0, 0, 0);

    // ---- kk=0, mi 4-7 ----
#pragma unroll
    for (int mi = 0; mi < 4; ++mi)
      af[mi] = *(const short8*)(Ac + arow + (mi + 4) * 2048 + (klo ^ aswz));
#pragma unroll
    for (int mi = 0; mi < 4; ++mi)
#pragma unroll
      for (int ni = 0; ni < 4; ++ni)
        acc[mi + 4][ni] = __builtin_amdgcn_mfma_f32_16x16x32_bf16(af[mi], bf[ni], acc[mi + 4][ni], 0, 0, 0);

    // ---- kk=1, mi 0-3 ----
#pragma unroll
    for (int ni = 0; ni < 4; ++ni)
      bf[ni] = *(const short8*)(Bc + 16384 + brd + ni * 1024);
#pragma unroll
    for (int mi = 0; mi < 4; ++mi)
      af[mi] = *(const short8*)(Ac + arow + mi * 2048 + ((64 + klo) ^ aswz));
#pragma unroll
    for (int mi = 0; mi < 4; ++mi)
#pragma unroll
      for (int ni = 0; ni < 4; ++ni)
        acc[mi][ni] = __builtin_amdgcn_mfma_f32_16x16x32_bf16(af[mi], bf[ni], acc[mi][ni], 0, 0, 0);

    // ---- kk=1, mi 4-7 ----
#pragma unroll
    for (int mi = 0; mi < 4; ++mi)
      af[mi] = *(const short8*)(Ac + arow + (mi + 4) * 2048 + ((64 + klo) ^ aswz));
#pragma unroll
    for (int mi = 0; mi < 4; ++mi)
#pragma unroll
      for (int ni = 0; ni < 4; ++ni)
        acc[mi + 4][ni] = __builtin_amdgcn_mfma_f32_16x16x32_bf16(af[mi], bf[ni], acc[mi + 4][ni], 0, 0, 0);

    // ---- chunk boundary: counted drain (A(c+1)+B(c+1) landed; B(c+2) in flight)
    if (c < NCHUNK - 2) asm volatile("s_waitcnt vmcnt(4)" ::: "memory");
    else                asm volatile("s_waitcnt vmcnt(0)" ::: "memory");
    BAR();
  }
#undef STAGE_A
#undef STAGE_B

  // ---- Epilogue ----
  const int  colb = wn * 64 + (lane & 15);
  const long rowb = m0 + wm * 128 + ((lane >> 4) << 2);
  if (m0 + BM <= M_TOTAL) {
#pragma unroll
    for (int ni = 0; ni < 4; ++ni) {
      const int col = colb + ni * 16;
      const float bv = bias[col];
#pragma unroll
      for (int mi = 0; mi < 8; ++mi)
#pragma unroll
        for (int rr = 0; rr < 4; ++rr)
          out[(rowb + mi * 16 + rr) * COUT + col] = acc[mi][ni][rr] + bv;
    }
  } else {
#pragma unroll
    for (int ni = 0; ni < 4; ++ni) {
      const int col = colb + ni * 16;
      const float bv = bias[col];
#pragma unroll
      for (int mi = 0; mi < 8; ++mi)
#pragma unroll
        for (int rr = 0; rr < 4; ++rr) {
          const long row = rowb + mi * 16 + rr;
          if (row < M_TOTAL) out[row * COUT + col] = acc[mi][ni][rr] + bv;
        }
    }
  }
}

// =================== fallback (used only if ws too small) ==========
__global__ __launch_bounds__(512, 2) void bconv_fb(
    const float* __restrict__ x, const char* __restrict__ bfragB,
    const float* __restrict__ bias, float* __restrict__ out) {
  extern __shared__ char lds[];
  char* A0 = lds;
  char* A1 = lds + 32768;
  char* B0 = lds + 65536;
  char* B1 = lds + 98304;
  char* B2 = lds + 131072;

  const int tid  = threadIdx.x;
  const int lane = tid & 63;
  const int wave = tid >> 6;
  const int wm   = wave >> 2;
  const int wn   = wave & 3;
  const int q = GRID_M >> 3, r = GRID_M & 7;
  const int xcd = (int)blockIdx.x & 7, ob = (int)blockIdx.x >> 3;
  const int bid = (xcd < r ? xcd * (q + 1) : r * (q + 1) + (xcd - r) * q) + ob;
  const long m0 = (long)bid * BM;

  const int srow = tid >> 1;
  long mrow = m0 + srow; if (mrow > M_TOTAL - 1) mrow = M_TOTAL - 1;
  int nimg = (int)(mrow / (OH_ * OW_));
  int r2   = (int)(mrow - (long)nimg * (OH_ * OW_));
  int oh   = r2 / OW_;
  int ow   = r2 - oh * OW_;
  const long xbase = (((long)nimg * HH + oh) * WW + ow) * CIN + (tid & 1) * 32;
  const int wswz = (srow & 7) << 4;
  const int wko  = (tid & 1) << 6;
  const int aswz = (lane & 7) << 4;
  const int klo  = (lane >> 4) << 4;
  const int arow = (wm * 128 + (lane & 15)) * 128;
  const int brd  = wn * 4096 + lane * 16;
  const int bstg = tid * 16;

  f32x4 acc[8][4];
#pragma unroll
  for (int i = 0; i < 8; ++i)
#pragma unroll
    for (int j = 0; j < 4; ++j) acc[i][j] = (f32x4){0.f, 0.f, 0.f, 0.f};

  float4 av[8];
  {
    const float* xp = x + xbase;
#pragma unroll
    for (int f = 0; f < 8; ++f) av[f] = *(const float4*)(xp + f * 4);
#pragma unroll
    for (int rr = 0; rr < 4; ++rr)
      gload16(bfragB + rr * 8192 + bstg, B0 + rr * 8192 + bstg);
#pragma unroll
    for (int rr = 0; rr < 4; ++rr)
      gload16(bfragB + 32768 + rr * 8192 + bstg, B1 + rr * 8192 + bstg);
#pragma unroll
    for (int j = 0; j < 4; ++j) {
      short8 v;
      v[0]=(short)f2bf(av[2*j].x); v[1]=(short)f2bf(av[2*j].y);
      v[2]=(short)f2bf(av[2*j].z); v[3]=(short)f2bf(av[2*j].w);
      v[4]=(short)f2bf(av[2*j+1].x); v[5]=(short)f2bf(av[2*j+1].y);
      v[6]=(short)f2bf(av[2*j+1].z); v[7]=(short)f2bf(av[2*j+1].w);
      *(short8*)(A0 + srow * 128 + ((wko + j * 16) ^ wswz)) = v;
    }
    LGKM0();
    asm volatile("s_waitcnt vmcnt(4)" ::: "memory");
    BAR();
  }

  int cm3 = 0;
#pragma unroll 1
  for (int c = 0; c < NCHUNK; ++c) {
    const char* Ac = (c & 1) ? A1 : A0;
    char*       An = (c & 1) ? A0 : A1;
    const char* Bc  = (cm3 == 0) ? B0 : ((cm3 == 1) ? B1 : B2);
    char*       Bn2 = (cm3 == 0) ? B2 : ((cm3 == 1) ? B0 : B1);
    cm3 = (cm3 == 2) ? 0 : cm3 + 1;
    short8 af[4], bf[4];

#pragma unroll
    for (int mi = 0; mi < 4; ++mi)
      af[mi] = *(const short8*)(Ac + arow + mi * 2048 + (klo ^ aswz));
#pragma unroll
    for (int ni = 0; ni < 4; ++ni)
      bf[ni] = *(const short8*)(Bc + brd + ni * 1024);
    if (c + 1 < NCHUNK) {
      const int t = (c + 1) >> 1;
      const long xo = ((t / 3) * WW + (t % 3)) * CIN + ((c + 1) & 1) * 64;
      const float* xp = x + xbase + xo;
#pragma unroll
      for (int f = 0; f < 8; ++f) av[f] = *(const float4*)(xp + f * 4);
    }
    if (c + 2 < NCHUNK) {
      const char* bsrc = bfragB + (long)(c + 2) * 32768;
#pragma unroll
      for (int rr = 0; rr < 4; ++rr)
        gload16(bsrc + rr * 8192 + bstg, Bn2 + rr * 8192 + bstg);
    }
#pragma unroll
    for (int mi = 0; mi < 4; ++mi)
#pragma unroll
      for (int ni = 0; ni < 4; ++ni)
        acc[mi][ni] = __builtin_amdgcn_mfma_f32_16x16x32_bf16(af[mi], bf[ni], acc[mi][ni], 0, 0, 0);

#pragma unroll
    for (int mi = 0; mi < 4; ++mi)
      af[mi] = *(const short8*)(Ac + arow + (mi + 4) * 2048 + (klo ^ aswz));
#pragma unroll
    for (int mi = 0; mi < 4; ++mi)
#pragma unroll
      for (int ni = 0; ni < 4; ++ni)
        acc[mi + 4][ni] = __builtin_amdgcn_mfma_f32_16x16x32_bf16(af[mi], bf[ni], acc[mi + 4][ni], 0, 0, 0);

#pragma unroll
    for (int ni = 0; ni < 4; ++ni)
      bf[ni] = *(const short8*)(Bc + 16384 + brd + ni * 1024);
#pragma unroll
    for (int mi = 0; mi < 4; ++mi)
      af[mi] = *(const short8*)(Ac + arow + mi * 2048 + ((64 + klo) ^ aswz));
#pragma unroll
    for (int mi = 0; mi < 4; ++mi)
#pragma unroll
      for (int ni = 0; ni < 4; ++ni)
        acc[mi][ni] = __builtin_amdgcn_mfma_f32_16x16x32_bf16(af[mi], bf[ni], acc[mi][ni], 0, 0, 0);

#pragma unroll
    for (int mi = 0; mi < 4; ++mi)
      af[mi] = *(const short8*)(Ac + arow + (mi + 4) * 2048 + ((64 + klo) ^ aswz));
    if (c + 1 < NCHUNK) {
#pragma unroll
      for (int j = 0; j < 4; ++j) {
        short8 v;
        v[0]=(short)f2bf(av[2*j].x); v[1]=(short)f2bf(av[2*j].y);
        v[2]=(short)f2bf(av[2*j].z); v[3]=(short)f2bf(av[2*j].w);
        v[4]=(short)f2bf(av[2*j+1].x); v[5]=(short)f2bf(av[2*j+1].y);
        v[6]=(short)f2bf(av[2*j+1].z); v[7]=(short)f2bf(av[2*j+1].w);
        *(short8*)(An + srow * 128 + ((wko + j * 16) ^ wswz)) = v;
      }
    }
#pragma unroll
    for (int mi = 0; mi < 4; ++mi)
#pragma unroll
      for (int ni = 0; ni < 4; ++ni)
        acc[mi + 4][ni] = __builtin_amdgcn_mfma_f32_16x16x32_bf16(af[mi], bf[ni], acc[mi + 4][ni], 0, 0, 0);

    LGKM0();
    asm volatile("s_waitcnt vmcnt(4)" ::: "memory");
    BAR();
  }

  const int  colb = wn * 64 + (lane & 15);
  const long rowb = m0 + wm * 128 + ((lane >> 4) << 2);
#pragma unroll
  for (int ni = 0; ni < 4; ++ni) {
    const int col = colb + ni * 16;
    const float bv = bias[col];
#pragma unroll
    for (int mi = 0; mi < 8; ++mi)
#pragma unroll
      for (int rr = 0; rr < 4; ++rr) {
        const long row = rowb + mi * 16 + rr;
        if (row < M_TOTAL) out[row * COUT + col] = acc[mi][ni][rr] + bv;
      }
  }
}

extern "C" void kernel_launch(void* const* d_in, const int* in_sizes, int n_in,
                              void* d_out, int out_size, void* d_ws, size_t ws_size,
                              hipStream_t stream) {
  const float* x    = (const float*)d_in[0];
  const float* kern = (const float*)d_in[1];
  const float* bias = (const float*)d_in[2];
  float* out = (float*)d_out;

  const size_t BPACK_BYTES = (size_t)NCHUNK * 32768;       // 589824
  const size_t XBF_BYTES   = (size_t)XBF_ELEMS * 2;        // 102760448

  if (ws_size >= XBF_BYTES + BPACK_BYTES) {
    unsigned short* xbf = (unsigned short*)d_ws;
    short8* bfrag = (short8*)((char*)d_ws + XBF_BYTES);
    (void)hipFuncSetAttribute((const void*)bconv,
                              hipFuncAttributeMaxDynamicSharedMemorySize, 163840);
    xcvt<<<dim3((unsigned)(XBF_ELEMS / (256 * 8))), dim3(256), 0, stream>>>(x, xbf);
    prep_weights<<<dim3(144), dim3(256), 0, stream>>>(kern, bfrag);
    bconv<<<dim3(GRID_M), dim3(512), 163840, stream>>>(xbf, (const char*)bfrag, bias, out);
  } else {
    short8* bfrag = (short8*)d_ws;
    (void)hipFuncSetAttribute((const void*)bconv_fb,
                              hipFuncAttributeMaxDynamicSharedMemorySize, 163840);
    prep_weights<<<dim3(144), dim3(256), 0, stream>>>(kern, bfrag);
    bconv_fb<<<dim3(GRID_M), dim3(512), 163840, stream>>>(x, (const char*)bfrag, bias, out);
  }
}

// Round 8
// 303.643 us; speedup vs baseline: 1.5996x; 1.1121x over previous
//
#include <hip/hip_runtime.h>
#include <hip/hip_bf16.h>

typedef __attribute__((ext_vector_type(8))) short short8;
typedef __attribute__((ext_vector_type(4))) float f32x4;

#define NB   32
#define HH   112
#define WW   112
#define CIN  128
#define OH_  110
#define OW_  110
#define COUT 256
#define NTAP 9
#define NCHUNK 18                      // 9 taps x 2 K-halves of 64
#define M_TOTAL (NB * OH_ * OW_)       // 387200
#define BM 128
#define GRID_M (M_TOTAL / BM)          // 3025 exactly, no tail
#define XBF_ELEMS ((long)NB * HH * WW * CIN)   // 51380224

__device__ __forceinline__ unsigned short f2bf(float f) {
  union { float f; unsigned u; } v; v.f = f;
  unsigned r = v.u + 0x7fffu + ((v.u >> 16) & 1u);  // round-to-nearest-even
  return (unsigned short)(r >> 16);
}

// ---- x fp32 -> bf16, one pass
__global__ void xcvt(const float* __restrict__ x, unsigned short* __restrict__ xbf) {
  long i = ((long)blockIdx.x * 256 + threadIdx.x) * 8;
  float4 a = *(const float4*)(x + i);
  float4 b = *(const float4*)(x + i + 4);
  short8 v;
  v[0]=(short)f2bf(a.x); v[1]=(short)f2bf(a.y); v[2]=(short)f2bf(a.z); v[3]=(short)f2bf(a.w);
  v[4]=(short)f2bf(b.x); v[5]=(short)f2bf(b.y); v[6]=(short)f2bf(b.z); v[7]=(short)f2bf(b.w);
  *(short8*)(xbf + i) = v;
}

// Binarize + pack weights in LDS-consumption order per (chunk, n-half):
// flat short8 idx = ((((chunk*2 + nh)*2 + kk)*8 + nb)*64 + lane  (16 KB per slice).
// n = nh*128 + nb*16 + (lane&15); ci = (chunk&1)*64 + kk*32 + (lane>>4)*8 + j; tap = chunk>>1.
__global__ void prep_weights(const float* __restrict__ kern, short8* __restrict__ bfrag) {
  int idx = blockIdx.x * 256 + threadIdx.x;   // 18*2*2*8*64 = 36864
  if (idx >= NCHUNK * 2 * 2 * 8 * 64) return;
  int lane  = idx & 63;
  int nb    = (idx >> 6) & 7;
  int kk    = (idx >> 9) & 1;
  int nh    = (idx >> 10) & 1;
  int chunk = idx >> 11;
  int tap   = chunk >> 1;
  int n     = nh * 128 + nb * 16 + (lane & 15);
  int cib   = (chunk & 1) * 64 + kk * 32 + ((lane >> 4) << 3);
  short8 v;
#pragma unroll
  for (int j = 0; j < 8; ++j) {
    float kv = kern[(tap * CIN + cib + j) * COUT + n];
    float hs = fminf(fmaxf((kv + 1.0f) * 0.5f, 0.0f), 1.0f);
    float wb = 2.0f * rintf(hs) - 1.0f;   // {-1,+1}, round-half-even
    v[j] = (short)f2bf(wb);
  }
  bfrag[idx] = v;
}

__device__ __forceinline__ void gload16(const char* g, char* l) {
  __builtin_amdgcn_global_load_lds(
      (const __attribute__((address_space(1))) unsigned int*)g,
      (__attribute__((address_space(3))) unsigned int*)l, 16, 0, 0);
}

#define BAR()    __builtin_amdgcn_s_barrier()

// ============ main kernel: 256 thr, BM=BN=128, 2x2 waves, 80 KB LDS ==========
__global__ __launch_bounds__(256, 2) void bconv(
    const unsigned short* __restrict__ xbf, const char* __restrict__ bfragB,
    const float* __restrict__ bias, float* __restrict__ out) {
  extern __shared__ char lds[];
  char* A0 = lds;             // 128 rows x 128 B (64 ci bf16), XOR-swz content
  char* A1 = lds + 16384;
  char* B0 = lds + 32768;     // 3-deep B ring, fragment-linear, 16 KB each
  char* B1 = lds + 49152;
  char* B2 = lds + 65536;     // total 81920 B -> exactly 2 blocks/CU

  const int tid  = threadIdx.x;
  const int lane = tid & 63;
  const int wave = tid >> 6;
  const int wm   = wave >> 1;   // 0..1 (64-row half)
  const int wn   = wave & 1;    // 0..1 (64-col band)
  const int nh   = blockIdx.y;  // N-half (0..1)

  // bijective XCD-chunked swizzle (m204) over 3025 M-blocks
  const int q = GRID_M >> 3, r = GRID_M & 7;
  const int xcd = (int)blockIdx.x & 7, ob = (int)blockIdx.x >> 3;
  const int bid = (xcd < r ? xcd * (q + 1) : r * (q + 1) + (xcd - r) * q) + ob;
  const long m0 = (long)bid * BM;

  // ---- A staging source (pre-swizzled, rule #21): lane stages rows
  //      wave*32 + i*8 + (lane>>3); 16B-chunk (lane&7)^(lane>>3) of 128 B row.
  const int lrow = lane >> 3;
  const int cswz = ((lane & 7) ^ lrow) << 4;
  const char* xbfc = (const char*)xbf;
  long rbase[4];
#pragma unroll
  for (int i = 0; i < 4; ++i) {
    long mrow = m0 + wave * 32 + i * 8 + lrow;   // always < M_TOTAL (exact tiling)
    int nimg = (int)(mrow / (OH_ * OW_));
    int r2   = (int)(mrow - (long)nimg * (OH_ * OW_));
    int oh   = r2 / OW_;
    int ow   = r2 - oh * OW_;
    rbase[i] = ((((long)nimg * HH + oh) * WW + ow) * CIN) * 2 + cswz;
  }
  const int adoff = wave * 4096 + lane * 16;   // A dest: + i*1024
  const int bstg  = tid * 16;                  // B dest/src slice: + r*4096

#define STAGE_A(Abuf, cN) do {                                               \
    const int t_ = (cN) >> 1;                                                \
    const long xo_ = (((long)(t_ / 3) * WW + (t_ % 3)) * CIN + ((cN) & 1) * 64) * 2; \
    _Pragma("unroll")                                                        \
    for (int i_ = 0; i_ < 4; ++i_)                                           \
      gload16(xbfc + rbase[i_] + xo_, (Abuf) + adoff + i_ * 1024);           \
  } while (0)

#define STAGE_B(Bbuf, cN) do {                                               \
    const char* bsrc_ = bfragB + ((long)(cN) * 2 + nh) * 16384;              \
    _Pragma("unroll")                                                        \
    for (int r_ = 0; r_ < 4; ++r_)                                           \
      gload16(bsrc_ + r_ * 4096 + bstg, (Bbuf) + r_ * 4096 + bstg);          \
  } while (0)

  // ---- fragment read addressing ----
  const int aswz = (lane & 7) << 4;
  const int klo  = (lane >> 4) << 4;
  const int arow = (wm * 64 + (lane & 15)) * 128;   // + mi*2048 + k-bytes
  const int brd  = wn * 4096 + lane * 16;           // + kk*8192 + ni*1024

  f32x4 acc[4][4];
#pragma unroll
  for (int i = 0; i < 4; ++i)
#pragma unroll
    for (int j = 0; j < 4; ++j) acc[i][j] = (f32x4){0.f, 0.f, 0.f, 0.f};

  // ---- prologue: A(0), B(0) landed; B(1) in flight ----
  STAGE_A(A0, 0);
  STAGE_B(B0, 0);
  STAGE_B(B1, 1);
  asm volatile("s_waitcnt vmcnt(4)" ::: "memory");
  BAR();

  int cm3 = 0;
#pragma unroll 1
  for (int c = 0; c < NCHUNK; ++c) {
    const char* Ac = (c & 1) ? A1 : A0;
    char*       An = (c & 1) ? A0 : A1;
    const char* Bc  = (cm3 == 0) ? B0 : ((cm3 == 1) ? B1 : B2);
    char*       Bn2 = (cm3 == 0) ? B2 : ((cm3 == 1) ? B0 : B1);
    cm3 = (cm3 == 2) ? 0 : cm3 + 1;

    short8 af[4], bf[4];

    // ---- kk=0 ----
#pragma unroll
    for (int mi = 0; mi < 4; ++mi)
      af[mi] = *(const short8*)(Ac + arow + mi * 2048 + (klo ^ aswz));
#pragma unroll
    for (int ni = 0; ni < 4; ++ni)
      bf[ni] = *(const short8*)(Bc + brd + ni * 1024);
    // prefetch next A / next-next B (inactive buffers; no reader this chunk)
    if (c + 1 < NCHUNK) STAGE_A(An, c + 1);
    if (c + 2 < NCHUNK) STAGE_B(Bn2, c + 2);
#pragma unroll
    for (int mi = 0; mi < 4; ++mi)
#pragma unroll
      for (int ni = 0; ni < 4; ++ni)
        acc[mi][ni] = __builtin_amdgcn_mfma_f32_16x16x32_bf16(af[mi], bf[ni], acc[mi][ni], 0, 0, 0);

    // ---- kk=1 ----
#pragma unroll
    for (int mi = 0; mi < 4; ++mi)
      af[mi] = *(const short8*)(Ac + arow + mi * 2048 + ((64 + klo) ^ aswz));
#pragma unroll
    for (int ni = 0; ni < 4; ++ni)
      bf[ni] = *(const short8*)(Bc + 8192 + brd + ni * 1024);
#pragma unroll
    for (int mi = 0; mi < 4; ++mi)
#pragma unroll
      for (int ni = 0; ni < 4; ++ni)
        acc[mi][ni] = __builtin_amdgcn_mfma_f32_16x16x32_bf16(af[mi], bf[ni], acc[mi][ni], 0, 0, 0);

    // ---- chunk boundary: counted drain (A(c+1)+B(c+1) landed; B(c+2) in flight)
    if (c < NCHUNK - 2) asm volatile("s_waitcnt vmcnt(4)" ::: "memory");
    else                asm volatile("s_waitcnt vmcnt(0)" ::: "memory");
    BAR();
  }
#undef STAGE_A
#undef STAGE_B

  // ---- Epilogue: C/D col=lane&15, row=(lane>>4)*4+r; no tail (exact tiling) ----
  const int  colb = nh * 128 + wn * 64 + (lane & 15);
  const long rowb = m0 + wm * 64 + ((lane >> 4) << 2);
#pragma unroll
  for (int ni = 0; ni < 4; ++ni) {
    const int col = colb + ni * 16;
    const float bv = bias[col];
#pragma unroll
    for (int mi = 0; mi < 4; ++mi)
#pragma unroll
      for (int rr = 0; rr < 4; ++rr)
        out[(rowb + mi * 16 + rr) * COUT + col] = acc[mi][ni][rr] + bv;
  }
}

extern "C" void kernel_launch(void* const* d_in, const int* in_sizes, int n_in,
                              void* d_out, int out_size, void* d_ws, size_t ws_size,
                              hipStream_t stream) {
  const float* x    = (const float*)d_in[0];
  const float* kern = (const float*)d_in[1];
  const float* bias = (const float*)d_in[2];
  float* out = (float*)d_out;

  const size_t XBF_BYTES = (size_t)XBF_ELEMS * 2;        // 102760448
  unsigned short* xbf = (unsigned short*)d_ws;
  short8* bfrag = (short8*)((char*)d_ws + XBF_BYTES);    // 589824 B

  (void)hipFuncSetAttribute((const void*)bconv,
                            hipFuncAttributeMaxDynamicSharedMemorySize, 81920);

  xcvt<<<dim3((unsigned)(XBF_ELEMS / (256 * 8))), dim3(256), 0, stream>>>(x, xbf);
  prep_weights<<<dim3(144), dim3(256), 0, stream>>>(kern, bfrag);
  bconv<<<dim3(GRID_M, 2), dim3(256), 81920, stream>>>(xbf, (const char*)bfrag, bias, out);
}

// Round 9
// 303.072 us; speedup vs baseline: 1.6027x; 1.0019x over previous
//
#include <hip/hip_runtime.h>
#include <hip/hip_bf16.h>

typedef __attribute__((ext_vector_type(8))) short short8;
typedef __attribute__((ext_vector_type(4))) float f32x4;

#define NB   32
#define HH   112
#define WW   112
#define CIN  128
#define OH_  110
#define OW_  110
#define COUT 256
#define NTAP 9
#define NCHUNK 18                      // 9 taps x 2 K-halves of 64
#define M_TOTAL (NB * OH_ * OW_)       // 387200
#define BM 128
#define GRID_M (M_TOTAL / BM)          // 3025 exactly, no tail
#define XBF_ELEMS ((long)NB * HH * WW * CIN)   // 51380224

__device__ __forceinline__ unsigned short f2bf(float f) {
  union { float f; unsigned u; } v; v.f = f;
  unsigned r = v.u + 0x7fffu + ((v.u >> 16) & 1u);  // round-to-nearest-even
  return (unsigned short)(r >> 16);
}

// ---- x fp32 -> bf16, one pass
__global__ void xcvt(const float* __restrict__ x, unsigned short* __restrict__ xbf) {
  long i = ((long)blockIdx.x * 256 + threadIdx.x) * 8;
  float4 a = *(const float4*)(x + i);
  float4 b = *(const float4*)(x + i + 4);
  short8 v;
  v[0]=(short)f2bf(a.x); v[1]=(short)f2bf(a.y); v[2]=(short)f2bf(a.z); v[3]=(short)f2bf(a.w);
  v[4]=(short)f2bf(b.x); v[5]=(short)f2bf(b.y); v[6]=(short)f2bf(b.z); v[7]=(short)f2bf(b.w);
  *(short8*)(xbf + i) = v;
}

// Binarize + pack weights in fragment-consumption order per (chunk, n-half):
// flat short8 idx = (((chunk*2 + nh)*2 + kk)*8 + nb)*64 + lane  (16 KB per slice).
// n = nh*128 + nb*16 + (lane&15); ci = (chunk&1)*64 + kk*32 + (lane>>4)*8 + j; tap = chunk>>1.
__global__ void prep_weights(const float* __restrict__ kern, short8* __restrict__ bfrag) {
  int idx = blockIdx.x * 256 + threadIdx.x;   // 36864
  if (idx >= NCHUNK * 2 * 2 * 8 * 64) return;
  int lane  = idx & 63;
  int nb    = (idx >> 6) & 7;
  int kk    = (idx >> 9) & 1;
  int nh    = (idx >> 10) & 1;
  int chunk = idx >> 11;
  int tap   = chunk >> 1;
  int n     = nh * 128 + nb * 16 + (lane & 15);
  int cib   = (chunk & 1) * 64 + kk * 32 + ((lane >> 4) << 3);
  short8 v;
#pragma unroll
  for (int j = 0; j < 8; ++j) {
    float kv = kern[(tap * CIN + cib + j) * COUT + n];
    float hs = fminf(fmaxf((kv + 1.0f) * 0.5f, 0.0f), 1.0f);
    float wb = 2.0f * rintf(hs) - 1.0f;   // {-1,+1}, round-half-even
    v[j] = (short)f2bf(wb);
  }
  bfrag[idx] = v;
}

__device__ __forceinline__ void gload16(const char* g, char* l) {
  __builtin_amdgcn_global_load_lds(
      (const __attribute__((address_space(1))) unsigned int*)g,
      (__attribute__((address_space(3))) unsigned int*)l, 16, 0, 0);
}

#define BAR()    __builtin_amdgcn_s_barrier()
#define SCHED0() __builtin_amdgcn_sched_barrier(0)

// ==== main kernel: A via gload_lds (32 KB LDS), B direct L2->registers =======
__global__ __launch_bounds__(256, 2) void bconv(
    const unsigned short* __restrict__ xbf, const char* __restrict__ bfragB,
    const float* __restrict__ bias, float* __restrict__ out) {
  extern __shared__ char lds[];
  char* A0 = lds;             // 128 rows x 128 B (64 ci bf16), XOR-swz content
  char* A1 = lds + 16384;     // total 32 KB

  const int tid  = threadIdx.x;
  const int lane = tid & 63;
  const int wave = tid >> 6;
  const int wm   = wave >> 1;   // 0..1 (64-row half)
  const int wn   = wave & 1;    // 0..1 (64-col band)
  const int nh   = blockIdx.y;  // N-half (0..1)

  // bijective XCD-chunked swizzle (m204) over 3025 M-blocks
  const int q = GRID_M >> 3, r = GRID_M & 7;
  const int xcd = (int)blockIdx.x & 7, ob = (int)blockIdx.x >> 3;
  const int bid = (xcd < r ? xcd * (q + 1) : r * (q + 1) + (xcd - r) * q) + ob;
  const long m0 = (long)bid * BM;

  // ---- A staging source (pre-swizzled, rule #21): lane stages rows
  //      wave*32 + i*8 + (lane>>3); 16B-chunk (lane&7)^(lane>>3) of 128 B row.
  const int lrow = lane >> 3;
  const int cswz = ((lane & 7) ^ lrow) << 4;
  const char* xbfc = (const char*)xbf;
  long rbase[4];
#pragma unroll
  for (int i = 0; i < 4; ++i) {
    long mrow = m0 + wave * 32 + i * 8 + lrow;   // always < M_TOTAL (exact tiling)
    int nimg = (int)(mrow / (OH_ * OW_));
    int r2   = (int)(mrow - (long)nimg * (OH_ * OW_));
    int oh   = r2 / OW_;
    int ow   = r2 - oh * OW_;
    rbase[i] = ((((long)nimg * HH + oh) * WW + ow) * CIN) * 2 + cswz;
  }
  const int adoff = wave * 4096 + lane * 16;   // A dest: + i*1024

#define STAGE_A(Abuf, cN) do {                                               \
    const int t_ = (cN) >> 1;                                                \
    const long xo_ = (((long)(t_ / 3) * WW + (t_ % 3)) * CIN + ((cN) & 1) * 64) * 2; \
    _Pragma("unroll")                                                        \
    for (int i_ = 0; i_ < 4; ++i_)                                           \
      gload16(xbfc + rbase[i_] + xo_, (Abuf) + adoff + i_ * 1024);           \
  } while (0)

  // ---- B fragment source: slice for (chunk,nh); wave reads kk*8 + wn*4 + ni
  const char* bbase = bfragB + (long)nh * 16384 + lane * 16;
#define LOAD_B(dst, cN, kk_) do {                                            \
    const char* bs_ = bbase + (long)(cN) * 32768 + ((kk_) * 8 + wn * 4) * 1024; \
    _Pragma("unroll")                                                        \
    for (int ni_ = 0; ni_ < 4; ++ni_)                                        \
      (dst)[ni_] = *(const short8*)(bs_ + ni_ * 1024);                       \
  } while (0)

  // ---- A fragment read addressing ----
  const int aswz = (lane & 7) << 4;
  const int klo  = (lane >> 4) << 4;
  const int arow = (wm * 64 + (lane & 15)) * 128;   // + mi*2048 + k-bytes

  f32x4 acc[4][4];
#pragma unroll
  for (int i = 0; i < 4; ++i)
#pragma unroll
    for (int j = 0; j < 4; ++j) acc[i][j] = (f32x4){0.f, 0.f, 0.f, 0.f};

  short8 bb[2][2][4];   // [chunk parity][kk][ni] — statically indexed (full unroll)

  // ---- prologue: A(0) gloads FIRST, then B(0) reg loads; vmcnt(8) drains A ----
  STAGE_A(A0, 0);
  SCHED0();
  LOAD_B(bb[0][0], 0, 0);
  LOAD_B(bb[0][1], 0, 1);
  asm volatile("s_waitcnt vmcnt(8)" ::: "memory");
  BAR();

#pragma unroll
  for (int c = 0; c < NCHUNK; ++c) {
    const char* Ac = (c & 1) ? A1 : A0;
    char*       An = (c & 1) ? A0 : A1;
    const int   cur = c & 1, nxt = (c & 1) ^ 1;

    // A(c+1) gloads issue FIRST so boundary vmcnt(8) drains them
    if (c + 1 < NCHUNK) { STAGE_A(An, c + 1); SCHED0(); }

    short8 af[4];
    // ---- kk=0 ----
#pragma unroll
    for (int mi = 0; mi < 4; ++mi)
      af[mi] = *(const short8*)(Ac + arow + mi * 2048 + (klo ^ aswz));
    if (c + 1 < NCHUNK) LOAD_B(bb[nxt][0], c + 1, 0);
#pragma unroll
    for (int mi = 0; mi < 4; ++mi)
#pragma unroll
      for (int ni = 0; ni < 4; ++ni)
        acc[mi][ni] = __builtin_amdgcn_mfma_f32_16x16x32_bf16(af[mi], bb[cur][0][ni], acc[mi][ni], 0, 0, 0);

    // ---- kk=1 ----
#pragma unroll
    for (int mi = 0; mi < 4; ++mi)
      af[mi] = *(const short8*)(Ac + arow + mi * 2048 + ((64 + klo) ^ aswz));
    if (c + 1 < NCHUNK) LOAD_B(bb[nxt][1], c + 1, 1);
#pragma unroll
    for (int mi = 0; mi < 4; ++mi)
#pragma unroll
      for (int ni = 0; ni < 4; ++ni)
        acc[mi][ni] = __builtin_amdgcn_mfma_f32_16x16x32_bf16(af[mi], bb[cur][1][ni], acc[mi][ni], 0, 0, 0);

    // ---- chunk boundary: drain A(c+1) gloads only (B reg loads stay in flight)
    if (c + 1 < NCHUNK) {
      asm volatile("s_waitcnt vmcnt(8)" ::: "memory");
      BAR();
    }
  }
#undef STAGE_A
#undef LOAD_B

  // ---- Epilogue: C/D col=lane&15, row=(lane>>4)*4+r; no tail (exact tiling) ----
  const int  colb = nh * 128 + wn * 64 + (lane & 15);
  const long rowb = m0 + wm * 64 + ((lane >> 4) << 2);
#pragma unroll
  for (int ni = 0; ni < 4; ++ni) {
    const int col = colb + ni * 16;
    const float bv = bias[col];
#pragma unroll
    for (int mi = 0; mi < 4; ++mi)
#pragma unroll
      for (int rr = 0; rr < 4; ++rr)
        out[(rowb + mi * 16 + rr) * COUT + col] = acc[mi][ni][rr] + bv;
  }
}

extern "C" void kernel_launch(void* const* d_in, const int* in_sizes, int n_in,
                              void* d_out, int out_size, void* d_ws, size_t ws_size,
                              hipStream_t stream) {
  const float* x    = (const float*)d_in[0];
  const float* kern = (const float*)d_in[1];
  const float* bias = (const float*)d_in[2];
  float* out = (float*)d_out;

  const size_t XBF_BYTES = (size_t)XBF_ELEMS * 2;        // 102760448
  unsigned short* xbf = (unsigned short*)d_ws;
  short8* bfrag = (short8*)((char*)d_ws + XBF_BYTES);    // 589824 B

  (void)hipFuncSetAttribute((const void*)bconv,
                            hipFuncAttributeMaxDynamicSharedMemorySize, 32768);

  xcvt<<<dim3((unsigned)(XBF_ELEMS / (256 * 8))), dim3(256), 0, stream>>>(x, xbf);
  prep_weights<<<dim3(144), dim3(256), 0, stream>>>(kern, bfrag);
  bconv<<<dim3(GRID_M, 2), dim3(256), 32768, stream>>>(xbf, (const char*)bfrag, bias, out);
}